// Round 1
// baseline (19.142 us; speedup 1.0000x reference)
//
#include <hip/hip_runtime.h>
#include <math.h>

#define B_SZ   512
#define M_MIX  32
#define D_DIM  1024
#define T_MAX  4096
#define P3M    96    // 3 * M_MIX

// ---------------------------------------------------------------------------
// Kernel 1: partial GEMM. params_partial[ks][b][j] = sum_{d in chunk ks} q[b][d]*W[d][j]
// Grid: (128 row-groups, KS k-chunks). Block: 128 threads (j = 0..95 active).
// Query values are wave-uniform -> scalar loads; W access coalesced over j.
// ---------------------------------------------------------------------------
template<int KS>
__global__ __launch_bounds__(128) void params_kernel(const float* __restrict__ query,
                                                     const float* __restrict__ W,
                                                     float* __restrict__ ws)
{
    const int rg = blockIdx.x;      // group of 4 batch rows
    const int ks = blockIdx.y;      // k chunk
    const int j  = threadIdx.x;
    if (j >= P3M) return;
    const int chunk = D_DIM / KS;
    const int d0 = ks * chunk;
    const float* q0 = query + (size_t)(rg*4 + 0) * D_DIM + d0;
    const float* q1 = query + (size_t)(rg*4 + 1) * D_DIM + d0;
    const float* q2 = query + (size_t)(rg*4 + 2) * D_DIM + d0;
    const float* q3 = query + (size_t)(rg*4 + 3) * D_DIM + d0;
    const float* Wp = W + (size_t)d0 * P3M + j;
    float a0 = 0.f, a1 = 0.f, a2 = 0.f, a3 = 0.f;
    #pragma unroll 8
    for (int d = 0; d < chunk; ++d) {
        float w = Wp[(size_t)d * P3M];
        a0 = fmaf(q0[d], w, a0);
        a1 = fmaf(q1[d], w, a1);
        a2 = fmaf(q2[d], w, a2);
        a3 = fmaf(q3[d], w, a3);
    }
    float* o = ws + (size_t)ks * B_SZ * P3M + (size_t)(rg*4) * P3M + j;
    o[0*P3M] = a0; o[1*P3M] = a1; o[2*P3M] = a2; o[3*P3M] = a3;
}

// ---------------------------------------------------------------------------
// Kernel 2: per-row phi + masked normalize. One block (256 thr) per batch row.
// Thread handles t = tid + i*256, i in [0,16). Wave-uniform window skip prunes
// the Gaussian evaluation to the tiny active region around the kappas.
// ---------------------------------------------------------------------------
__global__ __launch_bounds__(256) void phi_kernel(const float* __restrict__ ws, int KS,
                                                  const float* __restrict__ bias,
                                                  const float* __restrict__ prev_kappa,
                                                  const int* __restrict__ seqlen,
                                                  float* __restrict__ out)
{
    __shared__ float sA[M_MIX];   // alpha
    __shared__ float sC[M_MIX];   // -beta * log2(e)
    __shared__ float sK[M_MIX];   // kappa
    __shared__ float sR[M_MIX];   // window half-width sqrt(37/beta)
    __shared__ float sRange[2];   // gmin, gmax over mixtures
    __shared__ float sRed[4];     // per-wave partial sums

    const int b   = blockIdx.x;
    const int tid = threadIdx.x;

    if (tid < P3M) {
        float p = bias[tid];
        for (int ks = 0; ks < KS; ++ks)
            p += ws[(size_t)ks * B_SZ * P3M + (size_t)b * P3M + tid];
        if (tid < M_MIX) {
            sA[tid] = __expf(p);
        } else if (tid < 2*M_MIX) {
            float be = __expf(p);
            sC[tid - M_MIX] = -be * 1.44269504f;
            sR[tid - M_MIX] = sqrtf(37.0f / be);
        } else {
            float ka = prev_kappa[(size_t)b * M_MIX + (tid - 2*M_MIX)] + __expf(p);
            sK[tid - 2*M_MIX] = ka;
            // next_kappa output (tail of d_out)
            out[(size_t)B_SZ * T_MAX + (size_t)b * M_MIX + (tid - 2*M_MIX)] = ka;
        }
    }
    __syncthreads();
    if (tid == 0) {
        float gmin = 1e30f, gmax = -1e30f;
        for (int m = 0; m < M_MIX; ++m) {
            gmin = fminf(gmin, sK[m] - sR[m]);
            gmax = fmaxf(gmax, sK[m] + sR[m]);
        }
        sRange[0] = gmin; sRange[1] = gmax;
    }
    __syncthreads();

    const float gmin = sRange[0], gmax = sRange[1];
    const float tf = (float)tid;
    const int wbase = tid & ~63;   // wave's first tid

    float acc[16];
    #pragma unroll
    for (int i = 0; i < 16; ++i) acc[i] = 0.f;

    #pragma unroll
    for (int i = 0; i < 16; ++i) {
        const float wlo = (float)(wbase + i * 256);
        // wave-uniform skip: does [wlo, wlo+63] intersect [gmin, gmax]?
        if (gmax >= wlo && gmin <= wlo + 63.0f) {
            const float t = tf + (float)(i * 256);
            #pragma unroll 4
            for (int m = 0; m < M_MIX; ++m) {
                float d = sK[m] - t;
                float arg = sC[m] * d * d;       // = -beta*d^2*log2(e)
                acc[i] += sA[m] * exp2f(arg);    // v_exp_f32
            }
        }
    }

    // mask + per-thread sum
    const int L = seqlen[b];
    float s = 0.f;
    #pragma unroll
    for (int i = 0; i < 16; ++i) {
        int t = tid + i * 256;
        if (t >= L) acc[i] = 0.f;
        s += acc[i];
    }
    // wave reduce (64 lanes)
    #pragma unroll
    for (int off = 32; off >= 1; off >>= 1) s += __shfl_xor(s, off);
    if ((tid & 63) == 0) sRed[tid >> 6] = s;
    __syncthreads();
    const float total = sRed[0] + sRed[1] + sRed[2] + sRed[3] + 1e-8f;
    const float invn = 1.0f / total;

    float* ob = out + (size_t)b * T_MAX;
    #pragma unroll
    for (int i = 0; i < 16; ++i)
        ob[tid + i * 256] = acc[i] * invn;
}

extern "C" void kernel_launch(void* const* d_in, const int* in_sizes, int n_in,
                              void* d_out, int out_size, void* d_ws, size_t ws_size,
                              hipStream_t stream) {
    const float* query = (const float*)d_in[0];
    const float* prevk = (const float*)d_in[1];
    const float* W     = (const float*)d_in[2];
    const float* bias  = (const float*)d_in[3];
    const int*   msl   = (const int*)d_in[4];
    float* out = (float*)d_out;
    float* ws  = (float*)d_ws;

    const size_t need4 = (size_t)4 * B_SZ * P3M * sizeof(float);
    if (ws_size >= need4) {
        params_kernel<4><<<dim3(128, 4), 128, 0, stream>>>(query, W, ws);
        phi_kernel<<<B_SZ, 256, 0, stream>>>(ws, 4, bias, prevk, msl, out);
    } else {
        params_kernel<1><<<dim3(128, 1), 128, 0, stream>>>(query, W, ws);
        phi_kernel<<<B_SZ, 256, 0, stream>>>(ws, 1, bias, prevk, msl, out);
    }
}

// Round 2
// 16.863 us; speedup vs baseline: 1.1352x; 1.1352x over previous
//
#include <hip/hip_runtime.h>
#include <math.h>

#define B_SZ   512
#define M_MIX  32
#define D_DIM  1024
#define T_MAX  4096
#define P3M    96    // 3 * M_MIX
#define ROWS   4     // batch rows per params block

// ---------------------------------------------------------------------------
// Kernel 1: split-K partial GEMM. ws[ks][b][j] = sum_{d in chunk ks} q[b][d]*W[d][j]
// Grid: (B/ROWS, KS). Block: 128 threads (j = 0..95 active for compute).
// q chunk staged in LDS (coalesced); W columns coalesced over j; 4 FMA chains.
// ---------------------------------------------------------------------------
template<int KS>
__global__ __launch_bounds__(128) void params_kernel(const float* __restrict__ query,
                                                     const float* __restrict__ W,
                                                     float* __restrict__ ws)
{
    constexpr int CHUNK = D_DIM / KS;
    __shared__ float sQ[ROWS][CHUNK];
    const int rg  = blockIdx.x;
    const int ks  = blockIdx.y;
    const int tid = threadIdx.x;
    const int d0  = ks * CHUNK;

    // stage q rows (coalesced)
    for (int idx = tid; idx < ROWS * CHUNK; idx += 128) {
        const int r = idx / CHUNK, d = idx % CHUNK;
        sQ[r][d] = query[(size_t)(rg * ROWS + r) * D_DIM + d0 + d];
    }
    __syncthreads();

    const int j = tid;
    if (j < P3M) {
        const float* Wp = W + (size_t)d0 * P3M + j;
        float a0 = 0.f, a1 = 0.f, a2 = 0.f, a3 = 0.f;
        #pragma unroll 8
        for (int d = 0; d < CHUNK; ++d) {
            const float w = Wp[(size_t)d * P3M];
            a0 = fmaf(sQ[0][d], w, a0);
            a1 = fmaf(sQ[1][d], w, a1);
            a2 = fmaf(sQ[2][d], w, a2);
            a3 = fmaf(sQ[3][d], w, a3);
        }
        float* o = ws + ((size_t)ks * B_SZ + (size_t)rg * ROWS) * P3M + j;
        o[0 * P3M] = a0; o[1 * P3M] = a1; o[2 * P3M] = a2; o[3 * P3M] = a3;
    }
}

// ---------------------------------------------------------------------------
// Kernel 2: per-row phi + masked normalize. One block (256 thr) per batch row.
// Thread handles t = tid + i*256. Wave-uniform window skip prunes the Gaussian
// evaluation to the active region around the kappas (terms < e^-37 dropped).
// ---------------------------------------------------------------------------
template<int KS>
__global__ __launch_bounds__(256) void phi_kernel(const float* __restrict__ ws,
                                                  const float* __restrict__ bias,
                                                  const float* __restrict__ prev_kappa,
                                                  const int* __restrict__ seqlen,
                                                  float* __restrict__ out)
{
    __shared__ float sA[M_MIX];   // alpha
    __shared__ float sC[M_MIX];   // -beta * log2(e)
    __shared__ float sK[M_MIX];   // kappa
    __shared__ float sR[M_MIX];   // window half-width sqrt(37/beta)
    __shared__ float sRange[2];   // gmin, gmax over mixtures
    __shared__ float sRed[4];     // per-wave partial sums

    const int b   = blockIdx.x;
    const int tid = threadIdx.x;

    if (tid < P3M) {
        float p = bias[tid];
        #pragma unroll
        for (int ks = 0; ks < KS; ++ks)
            p += ws[((size_t)ks * B_SZ + (size_t)b) * P3M + tid];
        if (tid < M_MIX) {
            sA[tid] = __expf(p);
        } else if (tid < 2 * M_MIX) {
            const float be = __expf(p);
            sC[tid - M_MIX] = -be * 1.44269504f;
            sR[tid - M_MIX] = sqrtf(37.0f / be);
        } else {
            const float ka = prev_kappa[(size_t)b * M_MIX + (tid - 2 * M_MIX)] + __expf(p);
            sK[tid - 2 * M_MIX] = ka;
            out[(size_t)B_SZ * T_MAX + (size_t)b * M_MIX + (tid - 2 * M_MIX)] = ka;
        }
    }
    __syncthreads();

    // parallel window reduce: 64 lanes, mixtures duplicated (m = tid&31)
    if (tid < 64) {
        const int m = tid & 31;
        float lo = sK[m] - sR[m];
        float hi = sK[m] + sR[m];
        #pragma unroll
        for (int off = 32; off >= 1; off >>= 1) {
            lo = fminf(lo, __shfl_xor(lo, off));
            hi = fmaxf(hi, __shfl_xor(hi, off));
        }
        if (tid == 0) { sRange[0] = lo; sRange[1] = hi; }
    }
    __syncthreads();

    const float gmin = sRange[0], gmax = sRange[1];
    const float tf = (float)tid;
    const int wbase = tid & ~63;   // wave's first tid

    float acc[16];
    #pragma unroll
    for (int i = 0; i < 16; ++i) acc[i] = 0.f;

    #pragma unroll
    for (int i = 0; i < 16; ++i) {
        const float wlo = (float)(wbase + i * 256);
        if (gmax >= wlo && gmin <= wlo + 63.0f) {   // wave-uniform skip
            const float t = tf + (float)(i * 256);
            #pragma unroll 4
            for (int m = 0; m < M_MIX; ++m) {
                const float d = sK[m] - t;
                acc[i] += sA[m] * exp2f(sC[m] * d * d);
            }
        }
    }

    // mask + per-thread sum
    const int L = seqlen[b];
    float s = 0.f;
    #pragma unroll
    for (int i = 0; i < 16; ++i) {
        const int t = tid + i * 256;
        if (t >= L) acc[i] = 0.f;
        s += acc[i];
    }
    #pragma unroll
    for (int off = 32; off >= 1; off >>= 1) s += __shfl_xor(s, off);
    if ((tid & 63) == 0) sRed[tid >> 6] = s;
    __syncthreads();
    const float invn = 1.0f / (sRed[0] + sRed[1] + sRed[2] + sRed[3] + 1e-8f);

    float* ob = out + (size_t)b * T_MAX;
    #pragma unroll
    for (int i = 0; i < 16; ++i)
        ob[tid + i * 256] = acc[i] * invn;
}

extern "C" void kernel_launch(void* const* d_in, const int* in_sizes, int n_in,
                              void* d_out, int out_size, void* d_ws, size_t ws_size,
                              hipStream_t stream) {
    const float* query = (const float*)d_in[0];
    const float* prevk = (const float*)d_in[1];
    const float* W     = (const float*)d_in[2];
    const float* bias  = (const float*)d_in[3];
    const int*   msl   = (const int*)d_in[4];
    float* out = (float*)d_out;
    float* ws  = (float*)d_ws;

    const size_t per_ks = (size_t)B_SZ * P3M * sizeof(float);
    if (ws_size >= 16 * per_ks) {
        params_kernel<16><<<dim3(B_SZ / ROWS, 16), 128, 0, stream>>>(query, W, ws);
        phi_kernel<16><<<B_SZ, 256, 0, stream>>>(ws, bias, prevk, msl, out);
    } else if (ws_size >= 4 * per_ks) {
        params_kernel<4><<<dim3(B_SZ / ROWS, 4), 128, 0, stream>>>(query, W, ws);
        phi_kernel<4><<<B_SZ, 256, 0, stream>>>(ws, bias, prevk, msl, out);
    } else {
        params_kernel<1><<<dim3(B_SZ / ROWS, 1), 128, 0, stream>>>(query, W, ws);
        phi_kernel<1><<<B_SZ, 256, 0, stream>>>(ws, bias, prevk, msl, out);
    }
}